// Round 2
// baseline (733.516 us; speedup 1.0000x reference)
//
#include <hip/hip_runtime.h>

// FNO spectral block: x(32,256,4096), weight(256,256,128,2) -> out (same dtype as x)
// Dtype (fp32 vs bf16 dataset) detected at runtime by probe_kernel; pipeline is
// bf16-MFMA internally with fp32 accumulation either way.
// Pipeline: probe -> basis -> GEMM1 (truncated rDFT) -> per-mode complex mix ->
// GEMM2 (irDFT) with LeakyReLU(0.2)+residual fused.

typedef unsigned short u16;
typedef unsigned int   u32;
typedef __attribute__((ext_vector_type(8))) short bf16x8;   // 8 bf16 = 4 VGPR
typedef __attribute__((ext_vector_type(4))) float f32x4;

#define NROWS 8192      // 32*256
#define MLEN  4096
#define NMODE 128

__device__ __forceinline__ u16 f2b(float f) {           // fp32 -> bf16 RNE
  u32 u = __float_as_uint(f);
  u += 0x7fffu + ((u >> 16) & 1u);
  return (u16)(u >> 16);
}
__device__ __forceinline__ float blo(u32 p) { return __uint_as_float(p << 16); }
__device__ __forceinline__ float bhi(u32 p) { return __uint_as_float(p & 0xffff0000u); }

// ------------------------------------------------------------- dtype probe
// fp32 data read as bf16 halfwords shows ~22% extreme exponents (>=0x8F);
// real bf16 N(0,1) data shows ~0%.  mode: 0 = fp32, 1 = bf16.
__global__ void probe_kernel(const u16* __restrict__ x16, int* __restrict__ flag) {
  __shared__ int cnt;
  if (threadIdx.x == 0) cnt = 0;
  __syncthreads();
  int c = 0;
  for (int j = threadIdx.x; j < 4096; j += 256) {
    u32 e = (x16[j] >> 7) & 0xFFu;
    if (e >= 0x8Fu) ++c;
  }
  atomicAdd(&cnt, c);
  __syncthreads();
  if (threadIdx.x == 0) flag[0] = (cnt > 256) ? 0 : 1;
}

// ---------------------------------------------------------------- basis
// Bas1[c][t] (256 x 4096): c<128 -> cos(2pi c t/4096), c>=128 -> -sin(2pi (c-128) t/4096)
// Bas2[t][c] (4096 x 256): same values transposed.
__global__ void basis_kernel(u16* __restrict__ Bas1, u16* __restrict__ Bas2) {
  int t = blockIdx.x;           // 0..4095
  int c = threadIdx.x;          // 0..255
  int m = c & 127;
  int idx = (m * t) & 4095;     // (m*t) mod N keeps the angle small & exact
  float theta = (float)idx * (6.283185307179586f / 4096.0f);
  float s, cth;
  __sincosf(theta, &s, &cth);
  float v = (c < 128) ? cth : -s;
  u16 bv = f2b(v);
  Bas2[t * 256 + c] = bv;
  Bas1[c * 4096 + t] = bv;
}

// ---------------------------------------------------------------- GEMM (NT)
// C = A(MxK, row-major, lda) * Bt(NxK, row-major, ldb)^T, bf16 in, fp32 acc.
// ADUAL: A may be fp32 (mode 0) -> convert during LDS staging.
// EPI=0: store C transposed as fp32 to C0[col*ldc+row]   (forward DFT -> Xt)
// EPI=1: out[row*ldc+col] = x + leakyrelu(C), dtype per mode.
template <int BM, int BN, int EPI, bool ADUAL>
__global__ __launch_bounds__(256)
void gemm_nt(const void* __restrict__ A, const u16* __restrict__ Bt,
             int K, int lda, int ldb,
             float* __restrict__ C0, int ldc,
             const void* __restrict__ xres, void* __restrict__ outp,
             const int* __restrict__ flag) {
  constexpr int LD = 72;                 // 64 + 8 bf16 pad: 4-bank shift/row, <=2-way
  constexpr int FM = BM / 32;
  constexpr int FN = BN / 32;
  __shared__ u16 As[BM * LD];
  __shared__ u16 Bs[BN * LD];
  const int mode = (ADUAL || EPI == 1) ? flag[0] : 1;
  const int tid = threadIdx.x;
  const int bn0 = blockIdx.x * BN;
  const int bm0 = blockIdx.y * BM;
  const int lane = tid & 63;
  const int wave = tid >> 6;
  const int wm = wave >> 1, wn = wave & 1;
  const int l15 = lane & 15, q4 = lane >> 4;

  f32x4 acc[FM][FN] = {};

  for (int kt = 0; kt < K; kt += 64) {
    __syncthreads();
    if (!ADUAL || mode == 1) {
      const u16* Ab = (const u16*)A;
#pragma unroll
      for (int q = tid; q < BM * 8; q += 256) {    // stage A (bf16): 16B/lane
        int row = q >> 3, c8 = q & 7;
        *(uint4*)&As[row * LD + c8 * 8] =
            *(const uint4*)&Ab[(size_t)(bm0 + row) * lda + kt + c8 * 8];
      }
    } else {
      const float* Af = (const float*)A;
#pragma unroll
      for (int q = tid; q < BM * 8; q += 256) {    // stage A (fp32 -> bf16)
        int row = q >> 3, c8 = q & 7;
        const float* src = &Af[(size_t)(bm0 + row) * lda + kt + c8 * 8];
        float4 f0 = *(const float4*)src;
        float4 f1 = *(const float4*)(src + 4);
        u16 tmp[8] = {f2b(f0.x), f2b(f0.y), f2b(f0.z), f2b(f0.w),
                      f2b(f1.x), f2b(f1.y), f2b(f1.z), f2b(f1.w)};
        *(uint4*)&As[row * LD + c8 * 8] = *(const uint4*)tmp;
      }
    }
#pragma unroll
    for (int q = tid; q < BN * 8; q += 256) {      // stage B^T (always bf16)
      int row = q >> 3, c8 = q & 7;
      *(uint4*)&Bs[row * LD + c8 * 8] =
          *(const uint4*)&Bt[(size_t)(bn0 + row) * ldb + kt + c8 * 8];
    }
    __syncthreads();
#pragma unroll
    for (int kk = 0; kk < 2; ++kk) {
      const int ko = kk * 32 + q4 * 8;             // A/B frag: k = quad*8+j
      bf16x8 af[FM], bfr[FN];
#pragma unroll
      for (int mi = 0; mi < FM; ++mi)
        af[mi] = *(const bf16x8*)&As[(wm * (BM / 2) + mi * 16 + l15) * LD + ko];
#pragma unroll
      for (int ni = 0; ni < FN; ++ni)
        bfr[ni] = *(const bf16x8*)&Bs[(wn * (BN / 2) + ni * 16 + l15) * LD + ko];
#pragma unroll
      for (int mi = 0; mi < FM; ++mi)
#pragma unroll
        for (int ni = 0; ni < FN; ++ni)
          acc[mi][ni] = __builtin_amdgcn_mfma_f32_16x16x32_bf16(
              af[mi], bfr[ni], acc[mi][ni], 0, 0, 0);
    }
  }

  // epilogue; C/D layout: col = n0 + (lane&15), row = m0 + quad*4 + r
#pragma unroll
  for (int mi = 0; mi < FM; ++mi) {
#pragma unroll
    for (int ni = 0; ni < FN; ++ni) {
      const int col = bn0 + wn * (BN / 2) + ni * 16 + l15;
#pragma unroll
      for (int r = 0; r < 4; ++r) {
        const int row = bm0 + wm * (BM / 2) + mi * 16 + q4 * 4 + r;
        float v = acc[mi][ni][r];
        if (EPI == 0) {
          C0[(size_t)col * ldc + row] = v;         // transposed store -> Xt[c][row]
        } else {
          size_t idx = (size_t)row * ldc + col;
          float lr = (v >= 0.f ? v : 0.2f * v);
          if (mode == 1) {
            float xv = blo((u32)((const u16*)xres)[idx]);
            ((u16*)outp)[idx] = f2b(xv + lr);
          } else {
            float xv = ((const float*)xres)[idx];
            ((float*)outp)[idx] = xv + lr;
          }
        }
      }
    }
  }
}

// ---------------------------------------------------------------- mode mix
// Y[b,o,m] = sum_i X[b,i,m] * w[o,i,m]  (complex). Xt layout: [c][row], c<128 Re, c>=128 Im.
// Writes Y' bf16 pre-scaled for the inverse GEMM: Re *= (2/N) (1/N for m=0), Im *= 2/N.
__global__ __launch_bounds__(256)
void mix_kernel(const float* __restrict__ Xt, const void* __restrict__ w,
                u16* __restrict__ Yp, const int* __restrict__ flag) {
  const int m = blockIdx.x;     // 0..127
  const int och = blockIdx.y;   // 0..3 -> 64 output channels each
  __shared__ u32 Xs[NROWS];     // packed (re,im) bf16 per row r=b*256+i
  const int mode = flag[0];
  const int tid = threadIdx.x;
#pragma unroll
  for (int j = 0; j < 32; ++j) {
    int r = j * 256 + tid;
    float re = Xt[(size_t)m * NROWS + r];
    float im = Xt[(size_t)(m + 128) * NROWS + r];
    Xs[r] = (u32)f2b(re) | ((u32)f2b(im) << 16);
  }
  __syncthreads();

  const int o = och * 64 + (tid & 63);
  const int bg = tid >> 6;                  // 4 groups x 8 batches
  float ar[8] = {0, 0, 0, 0, 0, 0, 0, 0};
  float ai[8] = {0, 0, 0, 0, 0, 0, 0, 0};
  const int xbase = bg * 2048;

  if (mode == 1) {
    const u32* wbase = (const u32*)w + (size_t)o * 32768 + m;  // (o*256+i)*128+m pairs
    for (int i = 0; i < 256; ++i) {
      u32 wp = wbase[(size_t)i * 128];
      float wr = blo(wp), wi = bhi(wp);
#pragma unroll
      for (int bb = 0; bb < 8; ++bb) {
        u32 xp = Xs[xbase + bb * 256 + i];   // full-wave broadcast
        float xr = blo(xp), xi = bhi(xp);
        ar[bb] = fmaf(xr, wr, fmaf(-xi, wi, ar[bb]));
        ai[bb] = fmaf(xr, wi, fmaf(xi, wr, ai[bb]));
      }
    }
  } else {
    const float* wbase = (const float*)w + 2u * ((size_t)o * 32768 + m);
    for (int i = 0; i < 256; ++i) {
      float2 wp = *(const float2*)&wbase[(size_t)i * 256];
      float wr = wp.x, wi = wp.y;
#pragma unroll
      for (int bb = 0; bb < 8; ++bb) {
        u32 xp = Xs[xbase + bb * 256 + i];
        float xr = blo(xp), xi = bhi(xp);
        ar[bb] = fmaf(xr, wr, fmaf(-xi, wi, ar[bb]));
        ai[bb] = fmaf(xr, wi, fmaf(xi, wr, ai[bb]));
      }
    }
  }

  const float sRe = (m == 0) ? (1.0f / 4096.0f) : (2.0f / 4096.0f);
  const float sIm = 2.0f / 4096.0f;         // m=0 Im killed by sin(0)=0 basis row
#pragma unroll
  for (int bb = 0; bb < 8; ++bb) {
    int b = bg * 8 + bb;
    size_t row2 = (size_t)(b * 256 + o) * 256;
    Yp[row2 + m] = f2b(ar[bb] * sRe);
    Yp[row2 + m + 128] = f2b(ai[bb] * sIm);
  }
}

// ---------------------------------------------------------------- launch
extern "C" void kernel_launch(void* const* d_in, const int* in_sizes, int n_in,
                              void* d_out, int out_size, void* d_ws, size_t ws_size,
                              hipStream_t stream) {
  const void* x = d_in[0];                // (32,256,4096) fp32 or bf16
  const void* w = d_in[1];                // (256,256,128,2) fp32 or bf16

  char* ws = (char*)d_ws;
  int*   flag = (int*)(ws);                        // 4 B (region 1 MB)
  u16*   Bas1 = (u16*)(ws + (1u << 20));           // 256*4096 bf16 = 2 MB
  u16*   Bas2 = (u16*)(ws + (3u << 20));           // 4096*256 bf16 = 2 MB
  float* Xt   = (float*)(ws + (8u << 20));         // 256*8192 f32  = 8 MB
  u16*   Yp   = (u16*)(ws + (16u << 20));          // 8192*256 bf16 = 4 MB

  probe_kernel<<<dim3(1), dim3(256), 0, stream>>>((const u16*)x, flag);
  basis_kernel<<<dim3(4096), dim3(256), 0, stream>>>(Bas1, Bas2);

  // forward truncated rDFT: X = x(8192x4096) * Bas1(256x4096)^T -> Xt (transposed f32)
  gemm_nt<64, 128, 0, true><<<dim3(2, 128), dim3(256), 0, stream>>>(
      x, Bas1, MLEN, MLEN, MLEN, Xt, NROWS, nullptr, nullptr, flag);

  // per-mode complex channel mix -> Y' (bf16, irfft scaling folded in)
  mix_kernel<<<dim3(128, 4), dim3(256), 0, stream>>>(Xt, w, Yp, flag);

  // inverse DFT + LeakyReLU + residual: out = x + lrelu(Y'(8192x256) * Bas2(4096x256)^T)
  gemm_nt<128, 128, 1, false><<<dim3(32, 64), dim3(256), 0, stream>>>(
      Yp, Bas2, 256, 256, 256, nullptr, MLEN, x, d_out, flag);
}